// Round 8
// baseline (2936.242 us; speedup 1.0000x reference)
//
#include <hip/hip_runtime.h>
#include <math.h>

#define BB 128
#define TT 512
#define HH 128
#define G4 512      // 4*H
#define CC 128
#define WW 32

// ---- workspace layout (float slots) ----
#define OFF_FCWT  0                          // 16384
#define OFF_W1P   (OFF_FCWT + CC*HH)         // f16 permuted Whh1: 32768 slots
#define OFF_WI2P  (OFF_W1P  + G4*HH/2)
#define OFF_WH2P  (OFF_WI2P + G4*HH/2)
#define OFF_B1P   (OFF_WH2P + G4*HH/2)       // 512
#define OFF_WI1P  (OFF_B1P + G4)
#define OFF_B2P   (OFF_WI1P + G4)
#define OFF_H2A   (OFF_B2P + G4)             // [T][B][H] fp32 (read-only after k1)
#define OFF_DOLD  (OFF_H2A + TT*BB*HH)
#define OFF_DH    (OFF_DOLD + TT*BB)
#define OFF_MT    (OFF_DH + TT*BB)
#define OFF_ST    (OFF_MT + TT)

typedef _Float16 h2t __attribute__((ext_vector_type(2)));

__device__ __forceinline__ unsigned short f16b(float v) {
    return __builtin_bit_cast(unsigned short, (_Float16)v);
}
__device__ __forceinline__ float dot2f(unsigned int a, unsigned int b, float acc) {
#if defined(__has_builtin) && __has_builtin(__builtin_amdgcn_fdot2)
    return __builtin_amdgcn_fdot2(__builtin_bit_cast(h2t, a),
                                  __builtin_bit_cast(h2t, b), acc, false);
#else
    h2t av = __builtin_bit_cast(h2t, a), bv = __builtin_bit_cast(h2t, b);
    acc = fmaf((float)av.x, (float)bv.x, acc);
    acc = fmaf((float)av.y, (float)bv.y, acc);
    return acc;
#endif
}
__device__ __forceinline__ float rcpf(float x) {
#if defined(__has_builtin) && __has_builtin(__builtin_amdgcn_rcpf)
    return __builtin_amdgcn_rcpf(x);
#else
    return 1.f / x;
#endif
}
// sigma(v) if !isg, tanh(v) = 2*sigma(2v)-1 if isg
__device__ __forceinline__ float act(float v, bool isg) {
    float xin = isg ? v + v : v;
    float r = rcpf(1.f + __expf(-xin));
    return isg ? fmaf(2.f, r, -1.f) : r;
}

// DPP quad_perm helpers (pure VALU, quad-local, no DS-pipe traffic).
// xor1 = quad_perm[1,0,3,2] = 0xB1 ; xor2 = quad_perm[2,3,0,1] = 0x4E.
template <int CTRL>
__device__ __forceinline__ float dppadd(float v) {
#if defined(__has_builtin) && __has_builtin(__builtin_amdgcn_update_dpp)
    int m = __builtin_amdgcn_update_dpp(0, __builtin_bit_cast(int, v),
                                        CTRL, 0xf, 0xf, true);
    return v + __builtin_bit_cast(float, m);
#else
    return v + __shfl_xor(v, CTRL == 0xB1 ? 1 : 2);
#endif
}
template <int CTRL>
__device__ __forceinline__ float dppmov(float v) {
#if defined(__has_builtin) && __has_builtin(__builtin_amdgcn_update_dpp)
    int m = __builtin_amdgcn_update_dpp(0, __builtin_bit_cast(int, v),
                                        CTRL, 0xf, 0xf, true);
    return __builtin_bit_cast(float, m);
#else
    return __shfl_xor(v, CTRL == 0xB1 ? 1 : 2);
#endif
}

// 32 dot2: one 64-col row-slice (8 uint4 f16 weights) x state (8 uint4)
__device__ __forceinline__ void dot32(float& acc, const uint4* W, const uint4* S) {
    #pragma unroll
    for (int k = 0; k < 8; ++k) {
        acc = dot2f(W[k].x, S[k].x, acc);
        acc = dot2f(W[k].y, S[k].y, acc);
        acc = dot2f(W[k].z, S[k].z, acc);
        acc = dot2f(W[k].w, S[k].w, acc);
    }
}

// LDS-visibility barrier WITHOUT vmcnt drain (per-step h2a store stays in
// flight; nothing reads h2a until k1 completes).
#define STEP_BARRIER() asm volatile("s_waitcnt lgkmcnt(0)\n\ts_barrier" ::: "memory")

// K0: gate-interleaved (r = h*4 + g) f16 weight images + permuted biases +
// fcW transpose.  (unchanged)
__global__ __launch_bounds__(256) void k0_prep(
    const float* __restrict__ Whh1, const float* __restrict__ Wih2,
    const float* __restrict__ Whh2, const float* __restrict__ fcW,
    const float* __restrict__ Wih1,
    const float* __restrict__ bih1, const float* __restrict__ bhh1,
    const float* __restrict__ bih2, const float* __restrict__ bhh2,
    float* __restrict__ fcWT,
    unsigned short* __restrict__ w1p, unsigned short* __restrict__ wi2p,
    unsigned short* __restrict__ wh2p,
    float* __restrict__ b1p, float* __restrict__ wi1p, float* __restrict__ b2p)
{
    int idx = blockIdx.x * blockDim.x + threadIdx.x;
    if (idx < G4 * HH) {
        int r_old = idx >> 7, k = idx & 127;
        int g = r_old >> 7, h = r_old & 127;
        int dst = (h * 4 + g) * HH + k;
        w1p [dst] = f16b(Whh1[idx]);
        wi2p[dst] = f16b(Wih2[idx]);
        wh2p[dst] = f16b(Whh2[idx]);
    }
    if (idx < CC * HH) {
        int c = idx / HH, h = idx % HH;
        fcWT[h * CC + c] = fcW[idx];
    }
    if (idx < G4) {
        int g = idx >> 7, h = idx & 127;
        int rn = h * 4 + g;
        b1p [rn] = bih1[idx] + bhh1[idx];
        wi1p[rn] = Wih1[idx];
        b2p [rn] = bih2[idx] + bhh2[idx];
    }
}

// K1: 2 batches per block -> weight traffic amortized 2x.  64 blocks x 512
// threads; thread = (unit h = tid>>2, row-pair half = (tid>>1)&1, col half
// s = tid&1), identical to the proven R6 map.  Every weight dword (register-
// resident or L2-streamed -- the allocator decides, we stopped fighting it)
// feeds TWO dot2 accumulations.  Per-XCD weight stream halves (8 blocks
// instead of 16 share the L2), per-CU L2 share doubles: the measured ~3450
// cy/step L2-stream floor drops to ~1100 cy, leaving ~1900 cy of VALU as the
// new budget.  No pins, no AGPRs (R7's asm-volatile AGPR reads serialized
// the pipeline: 3x regression).
__global__ __launch_bounds__(512)
__attribute__((amdgpu_waves_per_eu(2, 2)))
void k1_lstm(
    const float* __restrict__ x,
    const float* __restrict__ b1p, const float* __restrict__ wi1p,
    const float* __restrict__ b2p,
    const unsigned short* __restrict__ w1p,
    const unsigned short* __restrict__ wi2p,
    const unsigned short* __restrict__ wh2p,
    float* __restrict__ h2a)
{
    __shared__ __align__(16) unsigned short h1h[2][2][HH];   // [bat][parity]
    __shared__ __align__(16) unsigned short c1h[2][2][HH];
    __shared__ __align__(16) unsigned short h2h[2][2][HH];
    __shared__ float xs[2][TT];

    const int tid  = threadIdx.x;
    const int b0   = blockIdx.x * 2;
    const int s    = tid & 1;            // col half: cols [64s, 64s+64)
    const int half = (tid >> 1) & 1;     // 0: rows (i,f) ; 1: rows (g,o)
    const int h    = tid >> 2;           // hidden unit 0..127
    const int gr0  = 4 * h + 2 * half;   // first owned gate-row
    const bool hB  = (half != 0);

    // ---- weights: 2 rows x 64-col half x 3 matrices -> 48 uint4 = 192 dw
    uint4 w1[2][8], wi2[2][8], wh2[2][8];
    #pragma unroll
    for (int rr = 0; rr < 2; ++rr) {
        const uint4* p1 = (const uint4*)(w1p  + (size_t)(gr0 + rr) * HH + 64 * s);
        const uint4* p2 = (const uint4*)(wi2p + (size_t)(gr0 + rr) * HH + 64 * s);
        const uint4* p3 = (const uint4*)(wh2p + (size_t)(gr0 + rr) * HH + 64 * s);
        #pragma unroll
        for (int k = 0; k < 8; ++k) {
            w1[rr][k] = p1[k]; wi2[rr][k] = p2[k]; wh2[rr][k] = p3[k];
        }
    }
    const float wi1v0 = wi1p[gr0],     b1v0 = b1p[gr0],     b2v0 = b2p[gr0];
    const float wi1v1 = wi1p[gr0 + 1], b1v1 = b1p[gr0 + 1], b2v1 = b2p[gr0 + 1];

    xs[0][tid] = x[(size_t)b0 * TT + tid];
    xs[1][tid] = x[(size_t)(b0 + 1) * TT + tid];
    if (tid < HH) {
        #pragma unroll
        for (int bb = 0; bb < 2; ++bb) {
            h1h[bb][0][tid] = 0; h1h[bb][1][tid] = 0;
            c1h[bb][0][tid] = 0; c1h[bb][1][tid] = 0;
            h2h[bb][0][tid] = 0; h2h[bb][1][tid] = 0;
        }
    }
    float c1r[2] = {0.f, 0.f}, c2r[2] = {0.f, 0.f};
    __syncthreads();

    float* outp[2];
    outp[0] = h2a + (size_t)b0 * HH + h;
    outp[1] = outp[0] + HH;

    // ---- prologue u=0: layer-1 only, h1(prev)=0 -> gates are scalar ----
    #pragma unroll
    for (int bb = 0; bb < 2; ++bb) {
        float g0 = fmaf(xs[bb][0], wi1v0, b1v0);
        float g1 = fmaf(xs[bb][0], wi1v1, b1v1);
        float e0 = act(g0, hB);                 // A: sig(i) ; B: tanh(g)
        float e1 = act(g1, false);              // A: sig(f) ; B: sig(o)
        float peer = dppmov<0x4E>(e0);          // A <- tanh(g)
        float cn1 = fmaf(e1, c1r[bb], e0 * peer); // valid on A
        c1r[bb] = hB ? c1r[bb] : cn1;
        float cnp = dppmov<0x4E>(cn1);          // B <- cn
        float hn1 = e1 * act(cnp, true);        // valid on B
        if (s == 0) {
            if (hB) h1h[bb][1][h] = f16b(hn1);
            else    c1h[bb][1][h] = f16b(cn1);
        }
    }
    STEP_BARRIER();

    // ---- main: u = 1 .. TT-1 (layer-1 at t=u, layer-2 at t=u-1) ----
    for (int u = 1; u < TT; ++u) {
        const int p = u & 1, q = p ^ 1;

        float a0[2], a1[2], d0[2], d1[2];
        uint4 sv[8];
        #pragma unroll
        for (int bb = 0; bb < 2; ++bb) {
            // layer-1 dots: h1h[bb][p] = h1(u-1)
            const uint4* hp = (const uint4*)&h1h[bb][p][64 * s];
            #pragma unroll
            for (int k = 0; k < 8; ++k) sv[k] = hp[k];
            a0[bb] = 0.f; a1[bb] = 0.f;
            dot32(a0[bb], w1[0], sv);
            dot32(a1[bb], w1[1], sv);
            // layer-2 dots: c1h[bb][p] = c1(u-1), h2h[bb][p] = h2(u-2)
            const uint4* cp = (const uint4*)&c1h[bb][p][64 * s];
            #pragma unroll
            for (int k = 0; k < 8; ++k) sv[k] = cp[k];
            d0[bb] = 0.f; d1[bb] = 0.f;
            dot32(d0[bb], wi2[0], sv);
            dot32(d1[bb], wi2[1], sv);
            const uint4* gp = (const uint4*)&h2h[bb][p][64 * s];
            #pragma unroll
            for (int k = 0; k < 8; ++k) sv[k] = gp[k];
            dot32(d0[bb], wh2[0], sv);
            dot32(d1[bb], wh2[1], sv);
        }

        #pragma unroll
        for (int bb = 0; bb < 2; ++bb) {
            // col-half reduce (pure DPP)
            float A0 = dppadd<0xB1>(a0[bb]);
            float A1 = dppadd<0xB1>(a1[bb]);
            float D0 = dppadd<0xB1>(d0[bb]);
            float D1 = dppadd<0xB1>(d1[bb]);
            const float xv = xs[bb][u];

            // ---- cell-1 (t=u) ----
            float g0 = A0 + fmaf(xv, wi1v0, b1v0);
            float g1 = A1 + fmaf(xv, wi1v1, b1v1);
            float e0 = act(g0, hB);
            float e1 = act(g1, false);
            float peer = dppmov<0x4E>(e0);
            float cn1 = fmaf(e1, c1r[bb], e0 * peer);
            c1r[bb] = hB ? c1r[bb] : cn1;
            float cnp1 = dppmov<0x4E>(cn1);
            float hn1 = e1 * act(cnp1, true);

            // ---- cell-2 (t=u-1) ----
            float f0 = D0 + b2v0;
            float f1 = D1 + b2v1;
            float u0 = act(f0, hB);
            float u1 = act(f1, false);
            float peer2 = dppmov<0x4E>(u0);
            float cn2 = fmaf(u1, c2r[bb], u0 * peer2);
            c2r[bb] = hB ? c2r[bb] : cn2;
            float cnp2 = dppmov<0x4E>(cn2);
            float hn2 = u1 * act(cnp2, true);

            if (s == 0) {
                if (hB) {
                    h1h[bb][q][h] = f16b(hn1);
                    h2h[bb][q][h] = f16b(hn2);
                    outp[bb][(size_t)(u - 1) * (BB * HH)] = hn2;
                } else {
                    c1h[bb][q][h] = f16b(cn1);
                }
            }
        }
        STEP_BARRIER();
    }

    // ---- epilogue u=TT: layer-2 only (t = TT-1), buffers p = TT&1 = 0 ----
    #pragma unroll
    for (int bb = 0; bb < 2; ++bb) {
        uint4 sv[8];
        const uint4* cp = (const uint4*)&c1h[bb][0][64 * s];
        #pragma unroll
        for (int k = 0; k < 8; ++k) sv[k] = cp[k];
        float d0 = 0.f, d1 = 0.f;
        dot32(d0, wi2[0], sv);
        dot32(d1, wi2[1], sv);
        const uint4* gp = (const uint4*)&h2h[bb][0][64 * s];
        #pragma unroll
        for (int k = 0; k < 8; ++k) sv[k] = gp[k];
        dot32(d0, wh2[0], sv);
        dot32(d1, wh2[1], sv);
        d0 = dppadd<0xB1>(d0); d1 = dppadd<0xB1>(d1);
        float f0 = d0 + b2v0;
        float f1 = d1 + b2v1;
        float u0 = act(f0, hB);
        float u1 = act(f1, false);
        float peer2 = dppmov<0x4E>(u0);
        float cn2 = fmaf(u1, c2r[bb], u0 * peer2);
        float cnp2 = dppmov<0x4E>(cn2);
        float hn2 = u1 * act(cnp2, true);
        if (hB && s == 0) outp[bb][(size_t)(TT - 1) * (BB * HH)] = hn2;
    }
}

// K2: d_old[t,b] = h2[t,b,:].wt_old ; d_h[t,b] = h2[t,b,:].wt_h  (unchanged)
__global__ __launch_bounds__(256) void k2_dots(
    const float* __restrict__ h2a, const float* __restrict__ w_t,
    float* __restrict__ dold, float* __restrict__ dh)
{
    const int lane = threadIdx.x & 63;
    const int wave = blockIdx.x * (blockDim.x >> 6) + (threadIdx.x >> 6);
    const int nw = gridDim.x * (blockDim.x >> 6);
    const float wh0 = w_t[lane],       wh1 = w_t[64 + lane];
    const float wo0 = w_t[128 + lane], wo1 = w_t[192 + lane];
    for (int row = wave; row < TT * BB; row += nw) {
        const float* p = h2a + (size_t)row * HH;
        float v0 = p[lane], v1 = p[64 + lane];
        float po = v0 * wo0 + v1 * wo1;
        float ph = v0 * wh0 + v1 * wh1;
        #pragma unroll
        for (int off = 32; off; off >>= 1) {
            po += __shfl_xor(po, off);
            ph += __shfl_xor(ph, off);
        }
        if (lane == 0) { dold[row] = po; dh[row] = ph; }
    }
}

// K3: per-t global softmax stats over valid (j,b): m[t], s[t]  (unchanged)
__global__ __launch_bounds__(256) void k3_stats(
    const float* __restrict__ dold, const float* __restrict__ dh,
    float* __restrict__ mt, float* __restrict__ st)
{
    const int t = blockIdx.x;
    const int tid = threadIdx.x;
    const int cnt = (min(t, WW) + 1) * BB;
    const int jstart = max(t - (WW + 1), -1);

    float m = -INFINITY;
    for (int idx = tid; idx < cnt; idx += 256) {
        int jj = idx >> 7, b = idx & 127;
        int j = jstart + jj;
        float sc = dh[t * BB + b] + (j >= 0 ? dold[j * BB + b] : 0.f);
        m = fmaxf(m, sc);
    }
    #pragma unroll
    for (int off = 32; off; off >>= 1) m = fmaxf(m, __shfl_xor(m, off));
    __shared__ float rbuf[4];
    int wv = tid >> 6, ln = tid & 63;
    if (ln == 0) rbuf[wv] = m;
    __syncthreads();
    m = fmaxf(fmaxf(rbuf[0], rbuf[1]), fmaxf(rbuf[2], rbuf[3]));

    float s = 0.f;
    for (int idx = tid; idx < cnt; idx += 256) {
        int jj = idx >> 7, b = idx & 127;
        int j = jstart + jj;
        float sc = dh[t * BB + b] + (j >= 0 ? dold[j * BB + b] : 0.f);
        s += __expf(sc - m);
    }
    #pragma unroll
    for (int off = 32; off; off >>= 1) s += __shfl_xor(s, off);
    __shared__ float sbuf[4];
    if (ln == 0) sbuf[wv] = s;
    __syncthreads();
    if (tid == 0) { mt[t] = m; st[t] = sbuf[0] + sbuf[1] + sbuf[2] + sbuf[3]; }
}

// K45: fused attention + FC. grid (TT/8, BB), block 256.  (unchanged)
__global__ __launch_bounds__(256) void k45_attn_fc(
    const float* __restrict__ h2a,
    const float* __restrict__ dold, const float* __restrict__ dh,
    const float* __restrict__ mt, const float* __restrict__ st,
    const float* __restrict__ fcWT, const float* __restrict__ fcb,
    float* __restrict__ out)
{
    const int t0 = blockIdx.x * 8;
    const int b  = blockIdx.y;
    const int tid = threadIdx.x;

    __shared__ float hbuf[41][HH];     // rows t0-33 .. t0+7
    __shared__ float wjs[8][36];
    __shared__ float ytile[8][HH];

    for (int i = tid; i < 41 * 32; i += 256) {
        int r = i >> 5, q4 = i & 31;
        int t = t0 - 33 + r;
        float4 v = make_float4(0.f, 0.f, 0.f, 0.f);
        if (t >= 0)
            v = *(const float4*)(h2a + (size_t)t * (BB * HH) + (size_t)b * HH + q4 * 4);
        *(float4*)&hbuf[r][q4 * 4] = v;
    }
    for (int i = tid; i < 8 * 33; i += 256) {
        int tt = i / 33, ss = i % 33;
        int t = t0 + tt, j = t - 33 + ss;
        float w = 0.f;
        if (j >= 0)
            w = __expf(dold[j * BB + b] + dh[t * BB + b] - mt[t]) / st[t];
        wjs[tt][ss] = w;
    }
    __syncthreads();

    {
        const int tq = tid >> 5;
        const int hq = (tid & 31) * 4;
        float4 acc = *(const float4*)&hbuf[tq + 33][hq];   // h2[t]
        #pragma unroll 11
        for (int ss = 0; ss < 33; ++ss) {
            float w = wjs[tq][ss];
            float4 hb = *(const float4*)&hbuf[tq + ss][hq];
            acc.x = fmaf(w, hb.x, acc.x);
            acc.y = fmaf(w, hb.y, acc.y);
            acc.z = fmaf(w, hb.z, acc.z);
            acc.w = fmaf(w, hb.w, acc.w);
        }
        *(float4*)&ytile[tq][hq] = acc;
    }
    __syncthreads();

    {
        const int c  = tid & 127;
        const int th = tid >> 7;
        float acc[4];
        const float bias = fcb[c];
        #pragma unroll
        for (int i = 0; i < 4; ++i) acc[i] = bias;
        for (int hh = 0; hh < HH; ++hh) {
            float w = fcWT[hh * CC + c];
            #pragma unroll
            for (int i = 0; i < 4; ++i)
                acc[i] = fmaf(ytile[th * 4 + i][hh], w, acc[i]);
        }
        #pragma unroll
        for (int i = 0; i < 4; ++i) {
            int t = t0 + th * 4 + i;
            out[(size_t)b * (TT * CC) + (size_t)t * CC + c] = acc[i];
        }
    }
}

extern "C" void kernel_launch(void* const* d_in, const int* in_sizes, int n_in,
                              void* d_out, int out_size, void* d_ws, size_t ws_size,
                              hipStream_t stream)
{
    const float* x    = (const float*)d_in[0];
    const float* Wih1 = (const float*)d_in[1];
    const float* Whh1 = (const float*)d_in[2];
    const float* bih1 = (const float*)d_in[3];
    const float* bhh1 = (const float*)d_in[4];
    const float* Wih2 = (const float*)d_in[5];
    const float* Whh2 = (const float*)d_in[6];
    const float* bih2 = (const float*)d_in[7];
    const float* bhh2 = (const float*)d_in[8];
    const float* w_t  = (const float*)d_in[9];
    const float* fcW  = (const float*)d_in[10];
    const float* fcb  = (const float*)d_in[11];
    float* out = (float*)d_out;

    float* ws   = (float*)d_ws;
    float* fcWT = ws + OFF_FCWT;
    unsigned short* w1p  = (unsigned short*)(ws + OFF_W1P);
    unsigned short* wi2p = (unsigned short*)(ws + OFF_WI2P);
    unsigned short* wh2p = (unsigned short*)(ws + OFF_WH2P);
    float* b1pp = ws + OFF_B1P;
    float* wi1p = ws + OFF_WI1P;
    float* b2pp = ws + OFF_B2P;
    float* h2a  = ws + OFF_H2A;
    float* dold = ws + OFF_DOLD;
    float* dh   = ws + OFF_DH;
    float* mt   = ws + OFF_MT;
    float* st   = ws + OFF_ST;

    k0_prep<<<dim3((G4 * HH + 255) / 256), dim3(256), 0, stream>>>(
        Whh1, Wih2, Whh2, fcW, Wih1, bih1, bhh1, bih2, bhh2,
        fcWT, w1p, wi2p, wh2p, b1pp, wi1p, b2pp);

    k1_lstm<<<dim3(BB / 2), dim3(512), 0, stream>>>(
        x, b1pp, wi1p, b2pp, w1p, wi2p, wh2p, h2a);

    k2_dots<<<dim3(256), dim3(256), 0, stream>>>(h2a, w_t, dold, dh);

    k3_stats<<<dim3(TT), dim3(256), 0, stream>>>(dold, dh, mt, st);

    k45_attn_fc<<<dim3(TT / 8, BB), dim3(256), 0, stream>>>(
        h2a, dold, dh, mt, st, fcWT, fcb, out);
}

// Round 11
// 874.321 us; speedup vs baseline: 3.3583x; 3.3583x over previous
//
#include <hip/hip_runtime.h>
#include <math.h>

#define BB 128
#define TT 512
#define HH 128
#define G4 512      // 4*H
#define CC 128
#define WW 32
#define TCHUNK 128  // time chunk for k1b/k1c ping-pong (4 chunks)

// ---- workspace layout (float slots) ----
#define OFF_FCWT  0                          // 16384
#define OFF_W1P   (OFF_FCWT + CC*HH)         // f16 permuted Whh1: 32768 slots
#define OFF_WI2P  (OFF_W1P  + G4*HH/2)
#define OFF_WH2P  (OFF_WI2P + G4*HH/2)
#define OFF_B1P   (OFF_WH2P + G4*HH/2)       // 512
#define OFF_WI1P  (OFF_B1P + G4)
#define OFF_B2P   (OFF_WI1P + G4)
#define OFF_H2A   (OFF_B2P + G4)             // [T][B][H] fp32
#define OFF_DOLD  (OFF_H2A + TT*BB*HH)
#define OFF_DH    (OFF_DOLD + TT*BB)
#define OFF_MT    (OFF_DH + TT*BB)
#define OFF_ST    (OFF_MT + TT)
#define OFF_C1F   (OFF_ST + TT)              // f16 [t][b][h]: TT*BB*HH/2 slots
#define OFF_C2S   (OFF_C1F + TT*BB*HH/2)     // f32 [b][h] c2 checkpoint
#define OFF_GI2   (OFF_C2S + BB*HH)          // f32 [b][tc][r]: TCHUNK*BB*G4
// top = OFF_GI2 + TCHUNK*BB*G4 ~= 21.2M floats ~= 85 MB

typedef _Float16 h2t __attribute__((ext_vector_type(2)));

__device__ __forceinline__ unsigned short f16b(float v) {
    return __builtin_bit_cast(unsigned short, (_Float16)v);
}
__device__ __forceinline__ float dot2f(unsigned int a, unsigned int b, float acc) {
#if defined(__has_builtin) && __has_builtin(__builtin_amdgcn_fdot2)
    return __builtin_amdgcn_fdot2(__builtin_bit_cast(h2t, a),
                                  __builtin_bit_cast(h2t, b), acc, false);
#else
    h2t av = __builtin_bit_cast(h2t, a), bv = __builtin_bit_cast(h2t, b);
    acc = fmaf((float)av.x, (float)bv.x, acc);
    acc = fmaf((float)av.y, (float)bv.y, acc);
    return acc;
#endif
}
__device__ __forceinline__ float rcpf(float x) {
#if defined(__has_builtin) && __has_builtin(__builtin_amdgcn_rcpf)
    return __builtin_amdgcn_rcpf(x);
#else
    return 1.f / x;
#endif
}
// sigma(v) if !isg, tanh(v) = 2*sigma(2v)-1 if isg
__device__ __forceinline__ float act(float v, bool isg) {
    float xin = isg ? v + v : v;
    float r = rcpf(1.f + __expf(-xin));
    return isg ? fmaf(2.f, r, -1.f) : r;
}

// DPP quad_perm helpers (pure VALU, quad-local, no DS-pipe traffic).
template <int CTRL>
__device__ __forceinline__ float dppadd(float v) {
#if defined(__has_builtin) && __has_builtin(__builtin_amdgcn_update_dpp)
    int m = __builtin_amdgcn_update_dpp(0, __builtin_bit_cast(int, v),
                                        CTRL, 0xf, 0xf, true);
    return v + __builtin_bit_cast(float, m);
#else
    return v + __shfl_xor(v, CTRL == 0xB1 ? 1 : 2);
#endif
}
template <int CTRL>
__device__ __forceinline__ float dppmov(float v) {
#if defined(__has_builtin) && __has_builtin(__builtin_amdgcn_update_dpp)
    int m = __builtin_amdgcn_update_dpp(0, __builtin_bit_cast(int, v),
                                        CTRL, 0xf, 0xf, true);
    return __builtin_bit_cast(float, m);
#else
    return __shfl_xor(v, CTRL == 0xB1 ? 1 : 2);
#endif
}

// 32 dot2: one 64-col row-slice (8 uint4 f16 weights) x state (8 uint4)
__device__ __forceinline__ void dot32(float& acc, const uint4* W, const uint4* S) {
    #pragma unroll
    for (int k = 0; k < 8; ++k) {
        acc = dot2f(W[k].x, S[k].x, acc);
        acc = dot2f(W[k].y, S[k].y, acc);
        acc = dot2f(W[k].z, S[k].z, acc);
        acc = dot2f(W[k].w, S[k].w, acc);
    }
}

// LDS-visibility barrier WITHOUT vmcnt drain.
#define STEP_BARRIER() asm volatile("s_waitcnt lgkmcnt(0)\n\ts_barrier" ::: "memory")

// K0: gate-interleaved (r = h*4 + g) f16 weight images + permuted biases +
// fcW transpose.  (unchanged)
__global__ __launch_bounds__(256) void k0_prep(
    const float* __restrict__ Whh1, const float* __restrict__ Wih2,
    const float* __restrict__ Whh2, const float* __restrict__ fcW,
    const float* __restrict__ Wih1,
    const float* __restrict__ bih1, const float* __restrict__ bhh1,
    const float* __restrict__ bih2, const float* __restrict__ bhh2,
    float* __restrict__ fcWT,
    unsigned short* __restrict__ w1p, unsigned short* __restrict__ wi2p,
    unsigned short* __restrict__ wh2p,
    float* __restrict__ b1p, float* __restrict__ wi1p, float* __restrict__ b2p)
{
    int idx = blockIdx.x * blockDim.x + threadIdx.x;
    if (idx < G4 * HH) {
        int r_old = idx >> 7, k = idx & 127;
        int g = r_old >> 7, h = r_old & 127;
        int dst = (h * 4 + g) * HH + k;
        w1p [dst] = f16b(Whh1[idx]);
        wi2p[dst] = f16b(Wih2[idx]);
        wh2p[dst] = f16b(Whh2[idx]);
    }
    if (idx < CC * HH) {
        int c = idx / HH, h = idx % HH;
        fcWT[h * CC + c] = fcW[idx];
    }
    if (idx < G4) {
        int g = idx >> 7, h = idx & 127;
        int rn = h * 4 + g;
        b1p [rn] = bih1[idx] + bhh1[idx];
        wi1p[rn] = Wih1[idx];
        b2p [rn] = bih2[idx] + bhh2[idx];
    }
}

// K1a: LAYER-1 ONLY recurrence.  One matrix (Whh1) = 64 weight dwords/thread.
// Writes c1[t][b][h] f16 -- same quantization as the old LDS c1h handoff.
__global__ __launch_bounds__(512)
__attribute__((amdgpu_waves_per_eu(2, 2)))
void k1a_lstm1(
    const float* __restrict__ x,
    const float* __restrict__ b1p, const float* __restrict__ wi1p,
    const unsigned short* __restrict__ w1p,
    unsigned short* __restrict__ c1f)
{
    __shared__ __align__(16) unsigned short h1h[2][HH];
    __shared__ float xs[TT];

    const int tid  = threadIdx.x;
    const int b    = blockIdx.x;
    const int s    = tid & 1;            // col half
    const int half = (tid >> 1) & 1;     // 0: rows (i,f) ; 1: rows (g,o)
    const int h    = tid >> 2;
    const int gr0  = 4 * h + 2 * half;
    const bool hB  = (half != 0);

    uint4 w1[2][8];                      // 64 dwords
    #pragma unroll
    for (int rr = 0; rr < 2; ++rr) {
        const uint4* p1 = (const uint4*)(w1p + (size_t)(gr0 + rr) * HH + 64 * s);
        #pragma unroll
        for (int k = 0; k < 8; ++k) w1[rr][k] = p1[k];
    }
    const float wi1v0 = wi1p[gr0],     b1v0 = b1p[gr0];
    const float wi1v1 = wi1p[gr0 + 1], b1v1 = b1p[gr0 + 1];

    xs[tid] = x[(size_t)b * TT + tid];
    if (tid < HH) { h1h[0][tid] = 0; h1h[1][tid] = 0; }
    float c1reg = 0.f;
    __syncthreads();

    unsigned short* outc = c1f + (size_t)b * HH + h;   // [t][b][h]

    for (int u = 0; u < TT; ++u) {
        const int p = u & 1, q = p ^ 1;
        const float xv = xs[u];

        uint4 sv[8];
        const uint4* hp = (const uint4*)&h1h[p][64 * s];
        #pragma unroll
        for (int k = 0; k < 8; ++k) sv[k] = hp[k];
        float a0 = 0.f, a1 = 0.f;
        dot32(a0, w1[0], sv);
        dot32(a1, w1[1], sv);
        float A0 = dppadd<0xB1>(a0);
        float A1 = dppadd<0xB1>(a1);

        float g0 = A0 + fmaf(xv, wi1v0, b1v0);
        float g1 = A1 + fmaf(xv, wi1v1, b1v1);
        float e0 = act(g0, hB);                 // A: sig(i) ; B: tanh(g)
        float e1 = act(g1, false);              // A: sig(f) ; B: sig(o)
        float peer = dppmov<0x4E>(e0);
        float cn1 = fmaf(e1, c1reg, e0 * peer); // valid on A
        c1reg = hB ? c1reg : cn1;
        float cnp1 = dppmov<0x4E>(cn1);
        float hn1 = e1 * act(cnp1, true);       // valid on B
        if (s == 0) {
            if (hB) h1h[q][h] = f16b(hn1);
            else    outc[(size_t)u * (BB * HH)] = f16b(cn1);
        }
        STEP_BARRIER();
    }
}

// K1b: chunked batch GEMM gi2[b][tc][r] = f32( b2[r] + Wih2[r,:].c1[t0+tc,b,:] ).
// FIXED (R9/R10 bug): previously each thread claimed a full 128-col row but
// loaded only 64 cols -- half of K was silently dropped (identical 5.5e-2
// error in both rounds).  Now: 512 threads; thread = (row pair rq = tid>>1,
// col half s = tid&1): 2 rows x 64 cols = 16 uint4 = 64 weight dwords;
// adjacent lanes (tid^1) share rows, differ in col half -> dppadd<0xB1>
// completes the full-K sum; bias added AFTER the reduce; lane s writes row
// 2*rq+s.  Grid (TCHUNK/16, BB).
__global__ __launch_bounds__(512) void k1b_gemm(
    const unsigned short* __restrict__ c1f,
    const unsigned short* __restrict__ wi2p,
    const float* __restrict__ b2p,
    float* __restrict__ gi2, int t0)
{
    const int tl0 = blockIdx.x * 16;
    const int b   = blockIdx.y;
    const int tid = threadIdx.x;
    const int rq  = tid >> 1;            // row pair 0..255 -> rows 2rq, 2rq+1
    const int s   = tid & 1;             // col half

    __shared__ __align__(16) unsigned short c1t[16][HH];   // 4 KB
    {
        int row = tid >> 5;              // 0..15
        int col = (tid & 31) * 4;        // 0..124 halfwords
        *(uint2*)&c1t[row][col] =
            *(const uint2*)(c1f + ((size_t)(t0 + tl0 + row) * BB + b) * HH + col);
    }
    uint4 wa[8], wb[8];                  // rows 2rq, 2rq+1, col half s
    {
        const uint4* pa = (const uint4*)(wi2p + (size_t)(2 * rq) * HH + 64 * s);
        const uint4* pb = (const uint4*)(wi2p + (size_t)(2 * rq + 1) * HH + 64 * s);
        #pragma unroll
        for (int k = 0; k < 8; ++k) { wa[k] = pa[k]; wb[k] = pb[k]; }
    }
    const float bias = b2p[2 * rq + s];  // bias of the row THIS lane writes
    __syncthreads();

    float* gout = gi2 + ((size_t)b * TCHUNK + tl0) * G4;
    #pragma unroll 4
    for (int tt = 0; tt < 16; ++tt) {
        uint4 sv[8];
        const uint4* cp = (const uint4*)&c1t[tt][64 * s];
        #pragma unroll
        for (int k = 0; k < 8; ++k) sv[k] = cp[k];
        float d0 = 0.f, d1 = 0.f;
        dot32(d0, wa, sv);
        dot32(d1, wb, sv);
        float D0 = dppadd<0xB1>(d0);     // full-K sum, row 2rq
        float D1 = dppadd<0xB1>(d1);     // full-K sum, row 2rq+1
        float v  = (s ? D1 : D0) + bias;
        gout[(size_t)tt * G4 + 2 * rq + s] = v;
    }
}

// K1c: chunked LAYER-2 recurrence.  Whh2 (64 dw) register-resident; Wih2
// contribution read precomputed (f32 pair / thread / step).  c2 checkpointed
// between chunks; h2(t0-1) reseeded from h2a f32 (f32->f16 re-round is
// bit-identical to the in-loop f16 handoff).
__global__ __launch_bounds__(512)
__attribute__((amdgpu_waves_per_eu(2, 2)))
void k1c_lstm2(
    const float* __restrict__ gi2,
    const unsigned short* __restrict__ wh2p,
    float* __restrict__ h2a, float* __restrict__ c2s, int t0)
{
    __shared__ __align__(16) unsigned short h2h[2][HH];

    const int tid  = threadIdx.x;
    const int b    = blockIdx.x;
    const int s    = tid & 1;
    const int half = (tid >> 1) & 1;
    const int h    = tid >> 2;
    const int gr0  = 4 * h + 2 * half;
    const bool hB  = (half != 0);

    uint4 w2[2][8];                      // 64 dwords
    #pragma unroll
    for (int rr = 0; rr < 2; ++rr) {
        const uint4* p1 = (const uint4*)(wh2p + (size_t)(gr0 + rr) * HH + 64 * s);
        #pragma unroll
        for (int k = 0; k < 8; ++k) w2[rr][k] = p1[k];
    }

    if (tid < HH) {
        unsigned short hv = 0;
        if (t0 > 0) hv = f16b(h2a[((size_t)(t0 - 1) * BB + b) * HH + tid]);
        h2h[0][tid] = hv;
        h2h[1][tid] = 0;
    }
    float c2reg = (t0 > 0) ? c2s[b * HH + h] : 0.f;
    __syncthreads();

    const float* gbase = gi2 + (size_t)b * TCHUNK * G4 + gr0;
    float* outp = h2a + (size_t)b * HH + h;

    float2 gc = *(const float2*)gbase;   // tc=0 pair (rows gr0, gr0+1)
    for (int ts = 0; ts < TCHUNK; ++ts) {
        const int p = ts & 1, q = p ^ 1;

        float2 gn = make_float2(0.f, 0.f);
        if (ts + 1 < TCHUNK) gn = *(const float2*)(gbase + (size_t)(ts + 1) * G4);

        uint4 sv[8];
        const uint4* hp = (const uint4*)&h2h[p][64 * s];
        #pragma unroll
        for (int k = 0; k < 8; ++k) sv[k] = hp[k];
        float d0 = 0.f, d1 = 0.f;
        dot32(d0, w2[0], sv);
        dot32(d1, w2[1], sv);
        float D0 = dppadd<0xB1>(d0);
        float D1 = dppadd<0xB1>(d1);

        float f0 = D0 + gc.x;
        float f1 = D1 + gc.y;
        float e0 = act(f0, hB);
        float e1 = act(f1, false);
        float peer = dppmov<0x4E>(e0);
        float cn2 = fmaf(e1, c2reg, e0 * peer);
        c2reg = hB ? c2reg : cn2;
        float cnp2 = dppmov<0x4E>(cn2);
        float hn2 = e1 * act(cnp2, true);
        if (s == 0 && hB) {
            h2h[q][h] = f16b(hn2);
            outp[(size_t)(t0 + ts) * (BB * HH)] = hn2;
        }
        gc = gn;
        STEP_BARRIER();
    }
    if (s == 0 && !hB) c2s[b * HH + h] = c2reg;   // checkpoint for next chunk
}

// K2: d_old[t,b] = h2[t,b,:].wt_old ; d_h[t,b] = h2[t,b,:].wt_h  (unchanged)
__global__ __launch_bounds__(256) void k2_dots(
    const float* __restrict__ h2a, const float* __restrict__ w_t,
    float* __restrict__ dold, float* __restrict__ dh)
{
    const int lane = threadIdx.x & 63;
    const int wave = blockIdx.x * (blockDim.x >> 6) + (threadIdx.x >> 6);
    const int nw = gridDim.x * (blockDim.x >> 6);
    const float wh0 = w_t[lane],       wh1 = w_t[64 + lane];
    const float wo0 = w_t[128 + lane], wo1 = w_t[192 + lane];
    for (int row = wave; row < TT * BB; row += nw) {
        const float* p = h2a + (size_t)row * HH;
        float v0 = p[lane], v1 = p[64 + lane];
        float po = v0 * wo0 + v1 * wo1;
        float ph = v0 * wh0 + v1 * wh1;
        #pragma unroll
        for (int off = 32; off; off >>= 1) {
            po += __shfl_xor(po, off);
            ph += __shfl_xor(ph, off);
        }
        if (lane == 0) { dold[row] = po; dh[row] = ph; }
    }
}

// K3: per-t global softmax stats over valid (j,b): m[t], s[t]  (unchanged)
__global__ __launch_bounds__(256) void k3_stats(
    const float* __restrict__ dold, const float* __restrict__ dh,
    float* __restrict__ mt, float* __restrict__ st)
{
    const int t = blockIdx.x;
    const int tid = threadIdx.x;
    const int cnt = (min(t, WW) + 1) * BB;
    const int jstart = max(t - (WW + 1), -1);

    float m = -INFINITY;
    for (int idx = tid; idx < cnt; idx += 256) {
        int jj = idx >> 7, b = idx & 127;
        int j = jstart + jj;
        float sc = dh[t * BB + b] + (j >= 0 ? dold[j * BB + b] : 0.f);
        m = fmaxf(m, sc);
    }
    #pragma unroll
    for (int off = 32; off; off >>= 1) m = fmaxf(m, __shfl_xor(m, off));
    __shared__ float rbuf[4];
    int wv = tid >> 6, ln = tid & 63;
    if (ln == 0) rbuf[wv] = m;
    __syncthreads();
    m = fmaxf(fmaxf(rbuf[0], rbuf[1]), fmaxf(rbuf[2], rbuf[3]));

    float s = 0.f;
    for (int idx = tid; idx < cnt; idx += 256) {
        int jj = idx >> 7, b = idx & 127;
        int j = jstart + jj;
        float sc = dh[t * BB + b] + (j >= 0 ? dold[j * BB + b] : 0.f);
        s += __expf(sc - m);
    }
    #pragma unroll
    for (int off = 32; off; off >>= 1) s += __shfl_xor(s, off);
    __shared__ float sbuf[4];
    if (ln == 0) sbuf[wv] = s;
    __syncthreads();
    if (tid == 0) { mt[t] = m; st[t] = sbuf[0] + sbuf[1] + sbuf[2] + sbuf[3]; }
}

// K45: fused attention + FC. grid (TT/8, BB), block 256.  (unchanged)
__global__ __launch_bounds__(256) void k45_attn_fc(
    const float* __restrict__ h2a,
    const float* __restrict__ dold, const float* __restrict__ dh,
    const float* __restrict__ mt, const float* __restrict__ st,
    const float* __restrict__ fcWT, const float* __restrict__ fcb,
    float* __restrict__ out)
{
    const int t0 = blockIdx.x * 8;
    const int b  = blockIdx.y;
    const int tid = threadIdx.x;

    __shared__ float hbuf[41][HH];     // rows t0-33 .. t0+7
    __shared__ float wjs[8][36];
    __shared__ float ytile[8][HH];

    for (int i = tid; i < 41 * 32; i += 256) {
        int r = i >> 5, q4 = i & 31;
        int t = t0 - 33 + r;
        float4 v = make_float4(0.f, 0.f, 0.f, 0.f);
        if (t >= 0)
            v = *(const float4*)(h2a + (size_t)t * (BB * HH) + (size_t)b * HH + q4 * 4);
        *(float4*)&hbuf[r][q4 * 4] = v;
    }
    for (int i = tid; i < 8 * 33; i += 256) {
        int tt = i / 33, ss = i % 33;
        int t = t0 + tt, j = t - 33 + ss;
        float w = 0.f;
        if (j >= 0)
            w = __expf(dold[j * BB + b] + dh[t * BB + b] - mt[t]) / st[t];
        wjs[tt][ss] = w;
    }
    __syncthreads();

    {
        const int tq = tid >> 5;
        const int hq = (tid & 31) * 4;
        float4 acc = *(const float4*)&hbuf[tq + 33][hq];   // h2[t]
        #pragma unroll 11
        for (int ss = 0; ss < 33; ++ss) {
            float w = wjs[tq][ss];
            float4 hb = *(const float4*)&hbuf[tq + ss][hq];
            acc.x = fmaf(w, hb.x, acc.x);
            acc.y = fmaf(w, hb.y, acc.y);
            acc.z = fmaf(w, hb.z, acc.z);
            acc.w = fmaf(w, hb.w, acc.w);
        }
        *(float4*)&ytile[tq][hq] = acc;
    }
    __syncthreads();

    {
        const int c  = tid & 127;
        const int th = tid >> 7;
        float acc[4];
        const float bias = fcb[c];
        #pragma unroll
        for (int i = 0; i < 4; ++i) acc[i] = bias;
        for (int hh = 0; hh < HH; ++hh) {
            float w = fcWT[hh * CC + c];
            #pragma unroll
            for (int i = 0; i < 4; ++i)
                acc[i] = fmaf(ytile[th * 4 + i][hh], w, acc[i]);
        }
        #pragma unroll
        for (int i = 0; i < 4; ++i) {
            int t = t0 + th * 4 + i;
            out[(size_t)b * (TT * CC) + (size_t)t * CC + c] = acc[i];
        }
    }
}

extern "C" void kernel_launch(void* const* d_in, const int* in_sizes, int n_in,
                              void* d_out, int out_size, void* d_ws, size_t ws_size,
                              hipStream_t stream)
{
    const float* x    = (const float*)d_in[0];
    const float* Wih1 = (const float*)d_in[1];
    const float* Whh1 = (const float*)d_in[2];
    const float* bih1 = (const float*)d_in[3];
    const float* bhh1 = (const float*)d_in[4];
    const float* Wih2 = (const float*)d_in[5];
    const float* Whh2 = (const float*)d_in[6];
    const float* bih2 = (const float*)d_in[7];
    const float* bhh2 = (const float*)d_in[8];
    const float* w_t  = (const float*)d_in[9];
    const float* fcW  = (const float*)d_in[10];
    const float* fcb  = (const float*)d_in[11];
    float* out = (float*)d_out;

    float* ws   = (float*)d_ws;
    float* fcWT = ws + OFF_FCWT;
    unsigned short* w1p  = (unsigned short*)(ws + OFF_W1P);
    unsigned short* wi2p = (unsigned short*)(ws + OFF_WI2P);
    unsigned short* wh2p = (unsigned short*)(ws + OFF_WH2P);
    float* b1pp = ws + OFF_B1P;
    float* wi1p = ws + OFF_WI1P;
    float* b2pp = ws + OFF_B2P;
    float* h2a  = ws + OFF_H2A;
    float* dold = ws + OFF_DOLD;
    float* dh   = ws + OFF_DH;
    float* mt   = ws + OFF_MT;
    float* st   = ws + OFF_ST;
    unsigned short* c1f = (unsigned short*)(ws + OFF_C1F);
    float* c2s  = ws + OFF_C2S;
    float* gi2  = ws + OFF_GI2;

    k0_prep<<<dim3((G4 * HH + 255) / 256), dim3(256), 0, stream>>>(
        Whh1, Wih2, Whh2, fcW, Wih1, bih1, bhh1, bih2, bhh2,
        fcWT, w1p, wi2p, wh2p, b1pp, wi1p, b2pp);

    k1a_lstm1<<<dim3(BB), dim3(512), 0, stream>>>(
        x, b1pp, wi1p, w1p, c1f);

    for (int t0 = 0; t0 < TT; t0 += TCHUNK) {
        k1b_gemm<<<dim3(TCHUNK / 16, BB), dim3(512), 0, stream>>>(
            c1f, wi2p, b2pp, gi2, t0);
        k1c_lstm2<<<dim3(BB), dim3(512), 0, stream>>>(
            gi2, wh2p, h2a, c2s, t0);
    }

    k2_dots<<<dim3(256), dim3(256), 0, stream>>>(h2a, w_t, dold, dh);

    k3_stats<<<dim3(TT), dim3(256), 0, stream>>>(dold, dh, mt, st);

    k45_attn_fc<<<dim3(TT / 8, BB), dim3(256), 0, stream>>>(
        h2a, dold, dh, mt, st, fcWT, fcb, out);
}